// Round 1
// baseline (235.334 us; speedup 1.0000x reference)
//
#include <hip/hip_runtime.h>
#include <math.h>

#define N_POINTS 300000
#define K 64
#define P 32
#define DETC 1e-16f

// ws layout (floats): [0,64) N_k  | [64,128) S_k  | [128, 128+2048) M in [d][k] order
#define WS_FLOATS (K + K + K * P)

#define NBLOCKS 1280
#define NTHREADS 256

__global__ __launch_bounds__(NTHREADS) void em_pass(
    const float* __restrict__ mu_phi,
    const float* __restrict__ log_cov_phi,
    const float* __restrict__ pi_k,
    const float* __restrict__ mu_k,
    const float* __restrict__ log_cov_k,
    float* __restrict__ gamma_out,
    float* __restrict__ ws)
{
    const int lane = threadIdx.x & 63;                       // = cluster index
    const int wave = __builtin_amdgcn_readfirstlane(threadIdx.x >> 6);
    const int wavesPerBlock = NTHREADS >> 6;
    const int gw = blockIdx.x * wavesPerBlock + wave;        // global wave id (uniform)
    const int W  = gridDim.x * wavesPerBlock;

    // ---- per-lane cluster constants (persistent registers) ----
    float muk[P];
#pragma unroll
    for (int d = 0; d < P; ++d) muk[d] = mu_k[lane * P + d];
    const float lck  = log_cov_k[lane];
    const float icov = __expf(-lck);
    const float pik  = pi_k[lane];
    float n2k = 0.f;
#pragma unroll
    for (int d = 0; d < P; ++d) n2k = fmaf(muk[d], muk[d], n2k);

    // ---- per-lane accumulators ----
    float accN = 0.f, accS = 0.f;
    float accM[P];
#pragma unroll
    for (int d = 0; d < P; ++d) accM[d] = 0.f;

    const float Pf = (float)P;

    for (int i = gw; i < N_POINTS; i += W) {
        // wave-uniform point row -> broadcast loads
        const float4* row4 = reinterpret_cast<const float4*>(mu_phi) + (size_t)i * (P / 4);
        float m[P];
#pragma unroll
        for (int j = 0; j < P / 4; ++j) {
            float4 v = row4[j];
            m[4 * j + 0] = v.x; m[4 * j + 1] = v.y;
            m[4 * j + 2] = v.z; m[4 * j + 3] = v.w;
        }
        const float lcp = log_cov_phi[i];

        float dot = 0.f, n2i = 0.f;
#pragma unroll
        for (int d = 0; d < P; ++d) {
            dot = fmaf(m[d], muk[d], dot);
            n2i = fmaf(m[d], m[d], n2i);
        }
        const float sq   = n2i - 2.f * dot + n2k;
        const float elcp = __expf(lcp);
        const float KL   = 0.5f * (Pf * (lck - lcp) - Pf + Pf * elcp * icov + sq * icov);
        const float w    = pik * __expf(-KL);

        // butterfly wave-64 sum -> every lane holds sum(w)
        float sw = w;
#pragma unroll
        for (int off = 32; off; off >>= 1) sw += __shfl_xor(sw, off, 64);

        const float g = w * __builtin_amdgcn_rcpf(sw) + DETC;
        gamma_out[(size_t)i * K + lane] = g;                 // 256B coalesced store

        accN += g;
        accS  = fmaf(g, fmaf(Pf, elcp, n2i), accS);          // g*(P*exp(lcp) + ||phi||^2)
#pragma unroll
        for (int d = 0; d < P; ++d) accM[d] = fmaf(g, m[d], accM[d]);
    }

    // ---- block-level combine in LDS (M swizzled [d][k]: lanes hit consecutive banks) ----
    __shared__ float lN[K], lS[K], lM[K * P];
    for (int idx = threadIdx.x; idx < K; idx += NTHREADS) { lN[idx] = 0.f; lS[idx] = 0.f; }
    for (int idx = threadIdx.x; idx < K * P; idx += NTHREADS) lM[idx] = 0.f;
    __syncthreads();

    atomicAdd(&lN[lane], accN);
    atomicAdd(&lS[lane], accS);
#pragma unroll
    for (int d = 0; d < P; ++d) atomicAdd(&lM[d * K + lane], accM[d]);
    __syncthreads();

    // ---- one set of global atomics per block ----
    for (int idx = threadIdx.x; idx < K; idx += NTHREADS) {
        atomicAdd(&ws[idx], lN[idx]);
        atomicAdd(&ws[K + idx], lS[idx]);
    }
    for (int idx = threadIdx.x; idx < K * P; idx += NTHREADS)
        atomicAdd(&ws[2 * K + idx], lM[idx]);
}

__global__ void finalize(const float* __restrict__ ws, float* __restrict__ out_tail)
{
    const int k = threadIdx.x;   // 64 threads, one per cluster
    if (k >= K) return;
    const float Nk = ws[k];
    const float S  = ws[K + k];
    float* pi_new      = out_tail;            // 64
    float* mu_new      = out_tail + K;        // 64 x 32
    float* log_cov_new = out_tail + K + K * P;

    pi_new[k] = Nk / (float)N_POINTS;

    const float invN = 1.f / Nk;
    float m2 = 0.f;
#pragma unroll
    for (int d = 0; d < P; ++d) {
        const float m = ws[2 * K + d * K + k] * invN;
        mu_new[k * P + d] = m;
        m2 = fmaf(m, m, m2);
    }
    const float cov = (S - Nk * m2) / ((float)P * Nk);
    log_cov_new[k] = logf(cov);
}

extern "C" void kernel_launch(void* const* d_in, const int* in_sizes, int n_in,
                              void* d_out, int out_size, void* d_ws, size_t ws_size,
                              hipStream_t stream)
{
    const float* mu_phi      = (const float*)d_in[0];
    const float* log_cov_phi = (const float*)d_in[1];
    const float* pi_k        = (const float*)d_in[2];
    const float* mu_k        = (const float*)d_in[3];
    const float* log_cov_k   = (const float*)d_in[4];
    float* out = (float*)d_out;
    float* ws  = (float*)d_ws;

    hipMemsetAsync(ws, 0, WS_FLOATS * sizeof(float), stream);
    em_pass<<<NBLOCKS, NTHREADS, 0, stream>>>(mu_phi, log_cov_phi, pi_k, mu_k,
                                              log_cov_k, out, ws);
    finalize<<<1, 64, 0, stream>>>(ws, out + (size_t)N_POINTS * K);
}

// Round 2
// 203.684 us; speedup vs baseline: 1.1554x; 1.1554x over previous
//
#include <hip/hip_runtime.h>
#include <math.h>

#define NPTS 300000
#define K 64
#define P 32
#define DETC 1e-16f
// ws floats: [0,64) N_k | [64,128) S_k | [128,2176) M[d][k] | [2176] int counter
#define WS_FLOATS (K + K + K * P)

#define NBLOCKS 1024
#define NTHREADS 256
#define NWAVES (NBLOCKS * (NTHREADS / 64))            // 4096
#define CHUNK ((NPTS + NWAVES - 1) / NWAVES)          // 74

// ---- DPP helpers: sum across 64 lanes with VALU-only latency ----
#define DPP_ADD(v, ctrl)                                                     \
    v += __int_as_float(__builtin_amdgcn_update_dpp(                         \
        0, __float_as_int(v), (ctrl), 0xF, 0xF, true))

__device__ __forceinline__ float rl(float x, int lane) {
    return __int_as_float(__builtin_amdgcn_readlane(__float_as_int(x), lane));
}

__global__ __launch_bounds__(NTHREADS, 4) void em_pass(
    const float* __restrict__ mu_phi,
    const float* __restrict__ log_cov_phi,
    const float* __restrict__ pi_k,
    const float* __restrict__ mu_k,
    const float* __restrict__ log_cov_k,
    float* __restrict__ gamma_out,
    float* __restrict__ out_tail,   // pi_new | mu_new | log_cov_new
    float* __restrict__ ws)
{
    const int lane = threadIdx.x & 63;                 // = cluster index
    const int wave = threadIdx.x >> 6;
    const int gw = __builtin_amdgcn_readfirstlane(blockIdx.x * (NTHREADS / 64) + wave);

    // ---- per-lane cluster constants ----
    float muk[P];
#pragma unroll
    for (int d = 0; d < P; ++d) muk[d] = mu_k[lane * P + d];
    const float lck  = log_cov_k[lane];
    const float icov = __expf(-lck);
    const float pik  = pi_k[lane];
    float n2k = 0.f;
#pragma unroll
    for (int d = 0; d < P; ++d) n2k = fmaf(muk[d], muk[d], n2k);
    // KL = Ak - 16*lcp + 0.5*icov*u - icov*dot   (u = P*e^lcp + ||phi||^2)
    // w  = pik * exp(-KL);  fold ln(pik) into Ak
    const float Ak    = 0.5f * (32.f * lck - 32.f + icov * n2k) - __logf(pik);
    const float hicov = 0.5f * icov;

    float accN = 0.f, accS = 0.f;
    float accM[P];
#pragma unroll
    for (int d = 0; d < P; ++d) accM[d] = 0.f;

    const int start = gw * CHUNK;
    const int end0  = (start + CHUNK < NPTS) ? (start + CHUNK) : NPTS;

    for (int gb = start; gb < end0; gb += 64) {
        const int cnt = (end0 - gb < 64) ? (end0 - gb) : 64;

        // ---- divergent u-phase: lane = point. 8 independent float4 loads
        //      (8KB MLP per wave, warms L2 for the uniform re-reads below) ----
        float u_v = 0.f, lcp_v = 0.f;
        const int ip = gb + lane;
        if (lane < cnt) {
            const float4* r4 = reinterpret_cast<const float4*>(mu_phi + (size_t)ip * P);
            float4 a0 = r4[0], a1 = r4[1], a2 = r4[2], a3 = r4[3];
            float4 a4 = r4[4], a5 = r4[5], a6 = r4[6], a7 = r4[7];
            float n2 = 0.f;
#define N2ACC(q) n2 = fmaf(q.x,q.x,n2); n2 = fmaf(q.y,q.y,n2); \
                 n2 = fmaf(q.z,q.z,n2); n2 = fmaf(q.w,q.w,n2)
            N2ACC(a0); N2ACC(a1); N2ACC(a2); N2ACC(a3);
            N2ACC(a4); N2ACC(a5); N2ACC(a6); N2ACC(a7);
#undef N2ACC
            lcp_v = log_cov_phi[ip];
            u_v   = fmaf(32.f, __expf(lcp_v), n2);
        }

        // ---- per-point phase: lane = cluster; row via uniform (scalar) loads ----
#pragma unroll 2
        for (int p = 0; p < cnt; ++p) {
            const int i = gb + p;
            const float u_s    = rl(u_v, p);
            const float base_s = 16.f * rl(lcp_v, p);
            const float* row = mu_phi + (size_t)i * P;   // uniform -> s_load

            float dot = 0.f;
#pragma unroll
            for (int d = 0; d < P; ++d) dot = fmaf(row[d], muk[d], dot);

            // exponent = icov*dot + 16*lcp - 0.5*icov*u - Ak
            const float t = fmaf(-hicov, u_s, base_s) - Ak;
            const float w = __expf(fmaf(icov, dot, t));

            // wave-64 sum via DPP (VALU) + readlane combine
            float v = w;
            DPP_ADD(v, 0xB1);   // quad_perm xor1
            DPP_ADD(v, 0x4E);   // quad_perm xor2
            DPP_ADD(v, 0x128);  // row_ror:8
            DPP_ADD(v, 0x124);  // row_ror:4  -> each lane = its 16-row sum
            const float sum = (rl(v, 0) + rl(v, 16)) + (rl(v, 32) + rl(v, 48));

            const float g = fmaf(w, __builtin_amdgcn_rcpf(sum), DETC);
            gamma_out[(size_t)i * K + lane] = g;          // coalesced 256B

            accN += g;
            accS  = fmaf(g, u_s, accS);
#pragma unroll
            for (int d = 0; d < P; ++d) accM[d] = fmaf(g, row[d], accM[d]);
        }
    }

    // ---- block combine in LDS, then one set of global atomics ----
    __shared__ float lN[K], lS[K], lM[K * P];
    for (int idx = threadIdx.x; idx < K; idx += NTHREADS) { lN[idx] = 0.f; lS[idx] = 0.f; }
    for (int idx = threadIdx.x; idx < K * P; idx += NTHREADS) lM[idx] = 0.f;
    __syncthreads();

    atomicAdd(&lN[lane], accN);
    atomicAdd(&lS[lane], accS);
#pragma unroll
    for (int d = 0; d < P; ++d) atomicAdd(&lM[d * K + lane], accM[d]);
    __syncthreads();

    for (int idx = threadIdx.x; idx < K; idx += NTHREADS) {
        atomicAdd(&ws[idx], lN[idx]);
        atomicAdd(&ws[K + idx], lS[idx]);
    }
    for (int idx = threadIdx.x; idx < K * P; idx += NTHREADS)
        atomicAdd(&ws[2 * K + idx], lM[idx]);
    __syncthreads();   // all this block's global atomics drained (vmcnt(0))

    // ---- decoupled finalize: last block computes the small outputs ----
    __shared__ int lastf;
    if (threadIdx.x == 0) {
        __threadfence();
        const int c = atomicAdd((int*)(ws + WS_FLOATS), 1);
        lastf = (c == NBLOCKS - 1);
    }
    __syncthreads();
    if (lastf) {
        __threadfence();
        const int k = threadIdx.x;
        if (k < K) {
            const float Nk = __hip_atomic_load(&ws[k],     __ATOMIC_RELAXED, __HIP_MEMORY_SCOPE_AGENT);
            const float S  = __hip_atomic_load(&ws[K + k], __ATOMIC_RELAXED, __HIP_MEMORY_SCOPE_AGENT);
            float* pi_new      = out_tail;
            float* mu_new      = out_tail + K;
            float* log_cov_new = out_tail + K + K * P;

            pi_new[k] = Nk / (float)NPTS;
            const float invN = 1.f / Nk;
            float m2 = 0.f;
#pragma unroll
            for (int d = 0; d < P; ++d) {
                const float md = __hip_atomic_load(&ws[2 * K + d * K + k],
                                                   __ATOMIC_RELAXED, __HIP_MEMORY_SCOPE_AGENT) * invN;
                mu_new[k * P + d] = md;
                m2 = fmaf(md, md, m2);
            }
            const float cov = (S - Nk * m2) / (32.f * Nk);
            log_cov_new[k] = logf(cov);
        }
    }
}

extern "C" void kernel_launch(void* const* d_in, const int* in_sizes, int n_in,
                              void* d_out, int out_size, void* d_ws, size_t ws_size,
                              hipStream_t stream)
{
    const float* mu_phi      = (const float*)d_in[0];
    const float* log_cov_phi = (const float*)d_in[1];
    const float* pi_k        = (const float*)d_in[2];
    const float* mu_k        = (const float*)d_in[3];
    const float* log_cov_k   = (const float*)d_in[4];
    float* out = (float*)d_out;
    float* ws  = (float*)d_ws;

    hipMemsetAsync(ws, 0, (WS_FLOATS + 1) * sizeof(float), stream);
    em_pass<<<NBLOCKS, NTHREADS, 0, stream>>>(mu_phi, log_cov_phi, pi_k, mu_k,
                                              log_cov_k, out,
                                              out + (size_t)NPTS * K, ws);
}